// Round 6
// baseline (485.936 us; speedup 1.0000x reference)
//
#include <hip/hip_runtime.h>

#define LRELU_ALPHA 0.2f

typedef __attribute__((ext_vector_type(8))) short short8;
typedef __attribute__((ext_vector_type(4))) float float4v;
typedef __attribute__((ext_vector_type(2))) float f32x2;

__device__ __forceinline__ unsigned short f2bf(float f) {
  union { float f; unsigned u; } x; x.f = f;
  unsigned r = (x.u + 0x7fff + ((x.u >> 16) & 1)) >> 16;
  return (unsigned short)r;
}
__device__ __forceinline__ float bflo(unsigned u) {
  union { unsigned u; float f; } x; x.u = u << 16; return x.f;
}
__device__ __forceinline__ float bfhi(unsigned u) {
  union { unsigned u; float f; } x; x.u = u & 0xffff0000u; return x.f;
}
__device__ __forceinline__ f32x2 bfpair(unsigned u) {
  return (f32x2){bflo(u), bfhi(u)};
}
__device__ __forceinline__ unsigned packbf(float a, float b) {
  return (unsigned)f2bf(a) | ((unsigned)f2bf(b) << 16);
}

// =============================== Phase A: CSR build ===============================

__global__ __launch_bounds__(256) void k_count(const int* __restrict__ dst,
                                               int* __restrict__ cnt, int E) {
  int e = blockIdx.x * 256 + threadIdx.x;
  if (e < E) atomicAdd(&cnt[dst[e]], 1);
}

// wave-shfl scan (2 barriers instead of 20)
__global__ __launch_bounds__(1024) void k_scan1(const int* __restrict__ cnt,
                                                int* __restrict__ lscan,
                                                int* __restrict__ bsum, int N) {
  __shared__ int ws[16];
  int t = threadIdx.x, lane = t & 63, wid = t >> 6;
  int i = blockIdx.x * 1024 + t;
  int v = (i < N) ? cnt[i] : 0;
  int orig = v;
#pragma unroll
  for (int off = 1; off < 64; off <<= 1) {
    int y = __shfl_up(v, off, 64);
    if (lane >= off) v += y;
  }
  if (lane == 63) ws[wid] = v;
  __syncthreads();
  if (t < 16) {
    int s = ws[t], o = s;
#pragma unroll
    for (int off = 1; off < 16; off <<= 1) {
      int y = __shfl_up(s, off, 16);
      if (t >= off) s += y;
    }
    ws[t] = s - o;  // exclusive wave offsets
  }
  __syncthreads();
  if (i < N) lscan[i] = ws[wid] + v - orig;
  if (t == 1023) bsum[blockIdx.x] = ws[15] + v;
}

// one-wave shfl scan (nb <= 64)
__global__ __launch_bounds__(64) void k_scan2(int* __restrict__ bsum,
                                              int* __restrict__ rowptrN, int nb) {
  int t = threadIdx.x;
  int v = (t < nb) ? bsum[t] : 0;
  int orig = v;
  for (int off = 1; off < 64; off <<= 1) {
    int y = __shfl_up(v, off, 64);
    if (t >= off) v += y;
  }
  if (t < nb) bsum[t] = v - orig;
  if (t == 63) *rowptrN = v;
}

__global__ __launch_bounds__(1024) void k_scan3(int* __restrict__ rowptr,
                                                int* __restrict__ cur,
                                                const int* __restrict__ bsum, int N) {
  int i = blockIdx.x * 1024 + threadIdx.x;
  if (i < N) {
    int v = rowptr[i] + bsum[blockIdx.x];
    rowptr[i] = v;
    cur[i] = v;
  }
}

// pure CSR scatter: 4 edges/thread, pipelined atomics.
__global__ __launch_bounds__(256) void k_scatter(const int* __restrict__ src,
                                                 const int* __restrict__ dst,
                                                 const float* __restrict__ w,
                                                 int* __restrict__ cur,
                                                 uint2* __restrict__ edata, int E) {
  int base = (blockIdx.x * 256 + threadIdx.x) * 4;
  if (base >= E) return;
  int n = E - base; if (n > 4) n = 4;
  int ss[4], dd[4]; float ww[4];
  if (n == 4) {
    int4 s4 = *(const int4*)(src + base);
    int4 d4 = *(const int4*)(dst + base);
    float4 w4 = *(const float4*)(w + base);
    ss[0] = s4.x; ss[1] = s4.y; ss[2] = s4.z; ss[3] = s4.w;
    dd[0] = d4.x; dd[1] = d4.y; dd[2] = d4.z; dd[3] = d4.w;
    ww[0] = w4.x; ww[1] = w4.y; ww[2] = w4.z; ww[3] = w4.w;
  } else {
    for (int i = 0; i < n; ++i) { ss[i] = src[base + i]; dd[i] = dst[base + i]; ww[i] = w[base + i]; }
  }
  int pp[4];
#pragma unroll
  for (int i = 0; i < 4; ++i)
    if (i < n) pp[i] = atomicAdd(&cur[dd[i]], 1);
#pragma unroll
  for (int i = 0; i < 4; ++i)
    if (i < n) edata[pp[i]] = make_uint2((unsigned)ss[i], __float_as_uint(ww[i]));
}

// =============================== weight packing ===============================
// W0catT bf16 [256][128]: rows 0..127 GAT n=h*16+f -> W0[h,k,f]; rows 128..255 gcn_W0[k][n-128]
// logitW  fp32 [128][16] : c<8: va0_src[k][h=c]; c>=8: va0_dst[k][h=c-8]
// gw1T    bf16 [128][128]: gw1T[n][k] = gcn_W1[k][n]
// va1T    bf16 [16][128] : c<8: W1[h=c]@a1_src; c>=8: W1[h]@a1_dst
// WstackT bf16 [128][1024]: WstackT[n][h*128+k] = W1[h][k][n] * 0.125
__global__ __launch_bounds__(256) void k_pack(const float* __restrict__ W0,
                                              const float* __restrict__ a0s,
                                              const float* __restrict__ a0d,
                                              const float* __restrict__ W1,
                                              const float* __restrict__ a1s,
                                              const float* __restrict__ a1d,
                                              const float* __restrict__ gw0,
                                              const float* __restrict__ gw1,
                                              unsigned short* __restrict__ W0catT,
                                              float* __restrict__ logitW,
                                              unsigned short* __restrict__ gw1T,
                                              unsigned short* __restrict__ va1T,
                                              unsigned short* __restrict__ WstackT) {
  int idx = blockIdx.x * 256 + threadIdx.x;
  if (idx < 32768) {
    int n = idx >> 7, k = idx & 127;
    float v;
    if (n < 128) {
      int h = n >> 4, f = n & 15;
      v = W0[h * 2048 + k * 16 + f];
    } else {
      v = gw0[k * 128 + (n - 128)];
    }
    W0catT[idx] = f2bf(v);
  } else if (idx < 34816) {
    int j = idx - 32768;
    int k = j >> 4, c = j & 15;
    int h = (c < 8) ? c : c - 8;
    const float* a = (c < 8) ? a0s : a0d;
    float s = 0.f;
    for (int f = 0; f < 16; ++f) s += W0[h * 2048 + k * 16 + f] * a[h * 16 + f];
    logitW[j] = s;
  } else if (idx < 51200) {
    int j = idx - 34816;
    int n = j >> 7, k = j & 127;
    gw1T[j] = f2bf(gw1[k * 128 + n]);
  } else if (idx < 53248) {
    int j = idx - 51200;
    int c = j >> 7, k = j & 127;
    int h = c & 7;
    const float* a = (c < 8) ? a1s : a1d;
    float s = 0.f;
    for (int f = 0; f < 128; ++f) s += W1[h * 16384 + k * 128 + f] * a[h * 128 + f];
    va1T[j] = f2bf(s);
  } else if (idx < 184320) {
    int j = idx - 53248;
    int n = j >> 10, kk = j & 1023;
    int h = kk >> 7, k = kk & 127;
    WstackT[j] = f2bf(W1[h * 16384 + k * 128 + n] * 0.125f);
  }
}

// fused: xb = bf16(x), logit0[N,16] = x @ logitW; 16 rows per block
__global__ __launch_bounds__(256) void k_prep(const float* __restrict__ x,
                                              const float* __restrict__ logitW,
                                              unsigned short* __restrict__ xb,
                                              float* __restrict__ logit0, int N) {
  __shared__ float sm[16][132];
  __shared__ float sw[2048];
  int t = threadIdx.x;
  int base = blockIdx.x * 16;
  int r = t >> 4, cc = (t & 15) * 8;
  const float* xr = x + (size_t)(base + r) * 128 + cc;
  float4 v0 = *(const float4*)xr;
  float4 v1 = *(const float4*)(xr + 4);
  ushort4 o0 = {f2bf(v0.x), f2bf(v0.y), f2bf(v0.z), f2bf(v0.w)};
  ushort4 o1 = {f2bf(v1.x), f2bf(v1.y), f2bf(v1.z), f2bf(v1.w)};
  *(ushort4*)(xb + (size_t)(base + r) * 128 + cc) = o0;
  *(ushort4*)(xb + (size_t)(base + r) * 128 + cc + 4) = o1;
  *(float4*)&sm[r][cc] = v0;
  *(float4*)&sm[r][cc + 4] = v1;
  *(float4*)&sw[t * 8] = *(const float4*)(logitW + t * 8);
  *(float4*)&sw[t * 8 + 4] = *(const float4*)(logitW + t * 8 + 4);
  __syncthreads();
  int c = t & 15;
  float acc = 0.f;
#pragma unroll
  for (int k = 0; k < 128; ++k) acc += sm[r][k] * sw[k * 16 + c];
  logit0[(size_t)(base + r) * 16 + c] = acc;
}

// =============================== edge-weight precompute ===============================
// ISOLATED dispatch so the [N,16] logits table stays L2-resident (round-4 lesson).
__global__ __launch_bounds__(256) void k_pedge(const float* __restrict__ logits,
                                               const uint2* __restrict__ edata,
                                               const int* __restrict__ rowptr,
                                               unsigned short* __restrict__ pedge,
                                               float* __restrict__ linv, int N) {
  int wave = threadIdx.x >> 6, lane = threadIdx.x & 63;
  int d = blockIdx.x * 4 + wave;
  if (d >= N) return;
  int j8 = lane >> 3, h = lane & 7;
  float edv = logits[(size_t)d * 16 + 8 + h];
  int beg = rowptr[d], end = rowptr[d + 1];
  float lsum = 0.f;
  for (int ii = beg + j8; ii < end; ii += 8) {
    unsigned s = edata[ii].x;
    float es = logits[(size_t)s * 16 + h];
    float lg = es + edv;
    lg = lg > 0.f ? lg : LRELU_ALPHA * lg;
    float p = __expf(fminf(lg, 80.f));
    lsum += p;
    pedge[(size_t)ii * 8 + h] = f2bf(p);
  }
  lsum += __shfl_xor(lsum, 8, 64);
  lsum += __shfl_xor(lsum, 16, 64);
  lsum += __shfl_xor(lsum, 32, 64);
  if (lane < 8) linv[(size_t)d * 8 + h] = lsum > 0.f ? 1.f / lsum : 0.f;
}

// =============================== bf16 MFMA GEMM ===============================
// C = A[M,K] @ BT[Ncols,K]^T.
// EPI: 0 plain, 4 merged feat write: cc<128 -> bf16 at rr*192+cc; cc>=128 -> fp8
//      byte at rr*384 + 256 + (cc-128)  (one [N][384B] row: 256B bf16 + 128B fp8)
template <int NT, int OUT_BF16, int EPI>
__global__ __launch_bounds__(256) void k_mgemm(const unsigned short* __restrict__ A, int lda,
                                               const unsigned short* __restrict__ BT, int ldb,
                                               void* __restrict__ Cv, int ldc,
                                               const void* __restrict__ aux,
                                               int M, int Ncols, int K) {
  __shared__ unsigned short As[64][64];
  __shared__ unsigned short Bs[NT * 16][64];
  int tid = threadIdx.x;
  int w = tid >> 6, lane = tid & 63;
  int quad = lane >> 4, l16 = lane & 15;
  int row0 = blockIdx.x * 64;
  int c0 = blockIdx.y * (NT * 16);
  float4v acc[NT];
#pragma unroll
  for (int t = 0; t < NT; ++t) acc[t] = (float4v){0.f, 0.f, 0.f, 0.f};

  for (int k0 = 0; k0 < K; k0 += 64) {
    __syncthreads();
#pragma unroll
    for (int i = 0; i < 2; ++i) {
      int c = tid + i * 256;
      int r = c >> 3, kc = c & 7;
      uint4 v = {0u, 0u, 0u, 0u};
      int gr = row0 + r;
      if (gr < M) v = *(const uint4*)(A + (size_t)gr * lda + k0 + kc * 8);
      *(uint4*)(&As[r][(kc ^ (r & 7)) * 8]) = v;
    }
#pragma unroll
    for (int i = 0; i < (NT * 128 + 255) / 256; ++i) {
      int c = tid + i * 256;
      if (c < NT * 128) {
        int n = c >> 3, kc = c & 7;
        uint4 v = {0u, 0u, 0u, 0u};
        int gn = c0 + n;
        if (gn < Ncols) v = *(const uint4*)(BT + (size_t)gn * ldb + k0 + kc * 8);
        *(uint4*)(&Bs[n][(kc ^ (n & 7)) * 8]) = v;
      }
    }
    __syncthreads();
#pragma unroll
    for (int ks = 0; ks < 2; ++ks) {
      int m = w * 16 + l16;
      int ga = (ks * 4 + quad) ^ (m & 7);
      short8 a = *(const short8*)(&As[m][ga * 8]);
#pragma unroll
      for (int t = 0; t < NT; ++t) {
        int n = t * 16 + l16;
        int gb = (ks * 4 + quad) ^ (n & 7);
        short8 b = *(const short8*)(&Bs[n][gb * 8]);
        acc[t] = __builtin_amdgcn_mfma_f32_16x16x32_bf16(a, b, acc[t], 0, 0, 0);
      }
    }
  }
#pragma unroll
  for (int t = 0; t < NT; ++t) {
    int cc = c0 + t * 16 + l16;
    if (cc >= Ncols) continue;
#pragma unroll
    for (int i = 0; i < 4; ++i) {
      int rr = row0 + w * 16 + quad * 4 + i;
      if (rr >= M) continue;
      float v = acc[t][i];
      if (EPI == 4) {
        if (cc < 128) {
          ((unsigned short*)Cv)[(size_t)rr * 192 + cc] = f2bf(v);
        } else {
          int enc = __builtin_amdgcn_cvt_pk_fp8_f32(v, v, 0, false);
          ((unsigned char*)aux)[(size_t)rr * 384 + 256 + (cc - 128)] = (unsigned char)(enc & 0xff);
        }
      } else if (OUT_BF16)
        ((unsigned short*)Cv)[(size_t)rr * ldc + cc] = f2bf(v);
      else
        ((float*)Cv)[(size_t)rr * ldc + cc] = v;
    }
  }
}

// =============================== Phase F fused ===============================
// out[N,128] fp32 = max(aggbuf[N,1024] @ WstackT^T, relu(x2a[N,128] @ gw1T^T)).
// Pass 1 (K=128) -> base regs; pass 2 (K=1024) -> acc; combine. Kills the
// separate GCN-projection GEMM + its x2a write/read round trip.
__global__ __launch_bounds__(256) void k_fin(const unsigned short* __restrict__ A1,
                                             const unsigned short* __restrict__ B1,
                                             const unsigned short* __restrict__ A2,
                                             const unsigned short* __restrict__ B2,
                                             float* __restrict__ out, int M) {
  __shared__ unsigned short As[64][64];
  __shared__ unsigned short Bs[128][64];
  int tid = threadIdx.x;
  int w = tid >> 6, lane = tid & 63;
  int quad = lane >> 4, l16 = lane & 15;
  int row0 = blockIdx.x * 64;
  float4v acc[8], base[8];
#pragma unroll
  for (int t = 0; t < 8; ++t) acc[t] = (float4v){0.f, 0.f, 0.f, 0.f};
  // pass 1: relu(x2a @ gw1T^T), K=128
  for (int k0 = 0; k0 < 128; k0 += 64) {
    __syncthreads();
#pragma unroll
    for (int i = 0; i < 2; ++i) {
      int c = tid + i * 256;
      int r = c >> 3, kc = c & 7;
      uint4 v = {0u, 0u, 0u, 0u};
      int gr = row0 + r;
      if (gr < M) v = *(const uint4*)(A2 + (size_t)gr * 128 + k0 + kc * 8);
      *(uint4*)(&As[r][(kc ^ (r & 7)) * 8]) = v;
    }
#pragma unroll
    for (int i = 0; i < 4; ++i) {
      int c = tid + i * 256;
      int n = c >> 3, kc = c & 7;
      uint4 v = *(const uint4*)(B2 + (size_t)n * 128 + k0 + kc * 8);
      *(uint4*)(&Bs[n][(kc ^ (n & 7)) * 8]) = v;
    }
    __syncthreads();
#pragma unroll
    for (int ks = 0; ks < 2; ++ks) {
      int m = w * 16 + l16;
      int ga = (ks * 4 + quad) ^ (m & 7);
      short8 a = *(const short8*)(&As[m][ga * 8]);
#pragma unroll
      for (int t = 0; t < 8; ++t) {
        int n = t * 16 + l16;
        int gb = (ks * 4 + quad) ^ (n & 7);
        short8 b = *(const short8*)(&Bs[n][gb * 8]);
        acc[t] = __builtin_amdgcn_mfma_f32_16x16x32_bf16(a, b, acc[t], 0, 0, 0);
      }
    }
  }
#pragma unroll
  for (int t = 0; t < 8; ++t)
#pragma unroll
    for (int i = 0; i < 4; ++i) { base[t][i] = fmaxf(acc[t][i], 0.f); acc[t][i] = 0.f; }
  // pass 2: aggbuf @ WstackT^T, K=1024
  for (int k0 = 0; k0 < 1024; k0 += 64) {
    __syncthreads();
#pragma unroll
    for (int i = 0; i < 2; ++i) {
      int c = tid + i * 256;
      int r = c >> 3, kc = c & 7;
      uint4 v = {0u, 0u, 0u, 0u};
      int gr = row0 + r;
      if (gr < M) v = *(const uint4*)(A1 + (size_t)gr * 1024 + k0 + kc * 8);
      *(uint4*)(&As[r][(kc ^ (r & 7)) * 8]) = v;
    }
#pragma unroll
    for (int i = 0; i < 4; ++i) {
      int c = tid + i * 256;
      int n = c >> 3, kc = c & 7;
      uint4 v = *(const uint4*)(B1 + (size_t)n * 1024 + k0 + kc * 8);
      *(uint4*)(&Bs[n][(kc ^ (n & 7)) * 8]) = v;
    }
    __syncthreads();
#pragma unroll
    for (int ks = 0; ks < 2; ++ks) {
      int m = w * 16 + l16;
      int ga = (ks * 4 + quad) ^ (m & 7);
      short8 a = *(const short8*)(&As[m][ga * 8]);
#pragma unroll
      for (int t = 0; t < 8; ++t) {
        int n = t * 16 + l16;
        int gb = (ks * 4 + quad) ^ (n & 7);
        short8 b = *(const short8*)(&Bs[n][gb * 8]);
        acc[t] = __builtin_amdgcn_mfma_f32_16x16x32_bf16(a, b, acc[t], 0, 0, 0);
      }
    }
  }
#pragma unroll
  for (int t = 0; t < 8; ++t) {
    int cc = t * 16 + l16;
#pragma unroll
    for (int i = 0; i < 4; ++i) {
      int rr = row0 + w * 16 + quad * 4 + i;
      if (rr >= M) continue;
      out[(size_t)rr * 128 + cc] = fmaxf(acc[t][i], base[t][i]);
    }
  }
}

// =============================== Phase C: layer-0 aggregation ==============
// feat [N][384B] merged: [0,256) bf16 Wh0 pairs, [256,384) fp8 gcn-h0 pairs.
// p's staged from precomputed pedge; linv precomputed (k_pedge).
// Outputs: xh [N][512B] = 64 x uint2 { bf16 x1c pair | bf16 relu'd x2 pair }
// AND esed[N,16] fp32 = x1c @ va1T^T computed in-epilogue (f32 x1c, LDS va1T,
// wave-private reduction) — kills the Phase-D GEMM and the x1cc table.
__global__ __launch_bounds__(256, 8) void k_agg0(const unsigned short* __restrict__ feat,
                                                 const int* __restrict__ rowptr,
                                                 const uint2* __restrict__ edata,
                                                 const unsigned short* __restrict__ pedge,
                                                 const float* __restrict__ linv,
                                                 const unsigned short* __restrict__ va1T,
                                                 unsigned short* __restrict__ xh,
                                                 float* __restrict__ esed, int N) {
  __shared__ uint2 swl[4][64];
  __shared__ float pl[4][512];
  __shared__ unsigned short va1s[2048];
  __shared__ float xs[4][128];
  int wave = threadIdx.x >> 6, lane = threadIdx.x & 63;
  int head = lane >> 3;
  ((uint4*)va1s)[threadIdx.x] = ((const uint4*)va1T)[threadIdx.x];
  __syncthreads();
  const char* FG = (const char*)feat + lane * 4;        // + s*384: bf16 pair
  const char* FC = (const char*)feat + 256 + lane * 2;  // + s*384: fp8 pair
  for (int d = blockIdx.x * 4 + wave; d < N; d += gridDim.x * 4) {
    int beg = rowptr[d], end = rowptr[d + 1], deg = end - beg;
    f32x2 aa = {0.f, 0.f}, ga = {0.f, 0.f};
    float wsum = 0.f;
    for (int base = 0; base < deg; base += 64) {
      int idx = beg + base + lane;
      uint2 sv = make_uint2(0u, 0u);
      uint4 q = make_uint4(0u, 0u, 0u, 0u);
      if (idx < end) {
        sv = edata[idx];
        q = *(const uint4*)(pedge + (size_t)idx * 8);
      }
      swl[wave][lane] = sv;
      float4 pa = make_float4(bflo(q.x), bfhi(q.x), bflo(q.y), bfhi(q.y));
      float4 pb = make_float4(bflo(q.z), bfhi(q.z), bflo(q.w), bfhi(q.w));
      *(float4*)&pl[wave][lane * 8] = pa;
      *(float4*)&pl[wave][lane * 8 + 4] = pb;
      int ng = deg - base; if (ng > 64) ng = 64;
      int t = 0;
      for (; t + 4 <= ng; t += 4) {
        uint2 s0 = swl[wave][t], s1 = swl[wave][t + 1];
        uint2 s2 = swl[wave][t + 2], s3 = swl[wave][t + 3];
        unsigned g0 = *(const unsigned*)(FG + (size_t)s0.x * 384);
        unsigned g1 = *(const unsigned*)(FG + (size_t)s1.x * 384);
        unsigned g2 = *(const unsigned*)(FG + (size_t)s2.x * 384);
        unsigned g3 = *(const unsigned*)(FG + (size_t)s3.x * 384);
        unsigned c0 = *(const unsigned short*)(FC + (size_t)s0.x * 384);
        unsigned c1 = *(const unsigned short*)(FC + (size_t)s1.x * 384);
        unsigned c2 = *(const unsigned short*)(FC + (size_t)s2.x * 384);
        unsigned c3 = *(const unsigned short*)(FC + (size_t)s3.x * 384);
        float p0 = pl[wave][t * 8 + head];
        float p1 = pl[wave][t * 8 + 8 + head];
        float p2 = pl[wave][t * 8 + 16 + head];
        float p3 = pl[wave][t * 8 + 24 + head];
        float w0 = __uint_as_float(s0.y), w1 = __uint_as_float(s1.y);
        float w2 = __uint_as_float(s2.y), w3 = __uint_as_float(s3.y);
        aa += bfpair(g0) * p0; ga += __builtin_amdgcn_cvt_pk_f32_fp8(c0, false) * w0; wsum += w0;
        aa += bfpair(g1) * p1; ga += __builtin_amdgcn_cvt_pk_f32_fp8(c1, false) * w1; wsum += w1;
        aa += bfpair(g2) * p2; ga += __builtin_amdgcn_cvt_pk_f32_fp8(c2, false) * w2; wsum += w2;
        aa += bfpair(g3) * p3; ga += __builtin_amdgcn_cvt_pk_f32_fp8(c3, false) * w3; wsum += w3;
      }
      for (; t < ng; ++t) {
        uint2 s0 = swl[wave][t];
        unsigned g0 = *(const unsigned*)(FG + (size_t)s0.x * 384);
        unsigned c0 = *(const unsigned short*)(FC + (size_t)s0.x * 384);
        float p0 = pl[wave][t * 8 + head];
        float w0 = __uint_as_float(s0.y);
        aa += bfpair(g0) * p0; ga += __builtin_amdgcn_cvt_pk_f32_fp8(c0, false) * w0; wsum += w0;
      }
    }
    float inv = linv[(size_t)d * 8 + head];
    float v0 = aa.x * inv, v1 = aa.y * inv;
    v0 = v0 > 0.f ? v0 : __expf(v0) - 1.f;  // ELU
    v1 = v1 > 0.f ? v1 : __expf(v1) - 1.f;
    float ginv = 1.f / fmaxf(wsum, 1e-16f);
    ((uint2*)xh)[(size_t)d * 64 + lane] =
        make_uint2(packbf(v0, v1),
                   packbf(fmaxf(ga.x * ginv, 0.f), fmaxf(ga.y * ginv, 0.f)));
    // in-epilogue esed: wave-private LDS stage + dot with va1T + shfl reduce
    xs[wave][2 * lane] = v0;
    xs[wave][2 * lane + 1] = v1;
    int cc = lane & 15, g = lane >> 4;
    const unsigned short* vr = va1s + cc * 128 + g * 32;
    const float* xr = &xs[wave][g * 32];
    float part = 0.f;
#pragma unroll
    for (int j = 0; j < 32; ++j) part += xr[j] * bflo((unsigned)vr[j]);
    part += __shfl_xor(part, 16, 64);
    part += __shfl_xor(part, 32, 64);
    if (lane < 16) esed[(size_t)d * 16 + lane] = part;
  }
}

// =============================== Phase E: layer-1 aggregation ==============
// ONE uint2 (8B)/lane gather covers the full interleaved 512B xh row per edge:
// .x = bf16 x1c pair (GAT), .y = bf16 raw-x2 pair (GCN, projection deferred).
// Writes aggbuf [N,1024] bf16 + x2a [N,128] bf16 (raw; projected in k_fin).
__global__ __launch_bounds__(256, 8) void k_agg1(const unsigned short* __restrict__ xh,
                                                 const int* __restrict__ rowptr,
                                                 const uint2* __restrict__ edata,
                                                 const unsigned short* __restrict__ pedge,
                                                 const float* __restrict__ linv,
                                                 unsigned short* __restrict__ aggbuf,
                                                 unsigned short* __restrict__ x2a, int N) {
  __shared__ uint2 swl[4][64];
  __shared__ float pl[4][512];
  int wave = threadIdx.x >> 6, lane = threadIdx.x & 63;
  const uint2* X2 = (const uint2*)xh + lane;
  for (int d = blockIdx.x * 4 + wave; d < N; d += gridDim.x * 4) {
    int beg = rowptr[d], end = rowptr[d + 1], deg = end - beg;
    f32x2 axp[8] = {};
    f32x2 gp = {0.f, 0.f};
    float wsum = 0.f;
#define EDGE1(uu, ss, tt)                                    \
  {                                                          \
    float4 pv0 = *(const float4*)&pl[wave][(tt) * 8];        \
    float4 pv1 = *(const float4*)&pl[wave][(tt) * 8 + 4];    \
    float wj = __uint_as_float((ss).y);                      \
    f32x2 xA = bfpair((uu).x);                               \
    f32x2 hA = bfpair((uu).y);                               \
    axp[0] += xA * pv0.x; axp[1] += xA * pv0.y;              \
    axp[2] += xA * pv0.z; axp[3] += xA * pv0.w;              \
    axp[4] += xA * pv1.x; axp[5] += xA * pv1.y;              \
    axp[6] += xA * pv1.z; axp[7] += xA * pv1.w;              \
    gp += hA * wj; wsum += wj;                               \
  }
    for (int base = 0; base < deg; base += 64) {
      int idx = beg + base + lane;
      uint2 sv = make_uint2(0u, 0u);
      uint4 q = make_uint4(0u, 0u, 0u, 0u);
      if (idx < end) {
        sv = edata[idx];
        q = *(const uint4*)(pedge + (size_t)idx * 8);
      }
      swl[wave][lane] = sv;
      float4 pa = make_float4(bflo(q.x), bfhi(q.x), bflo(q.y), bfhi(q.y));
      float4 pb = make_float4(bflo(q.z), bfhi(q.z), bflo(q.w), bfhi(q.w));
      *(float4*)&pl[wave][lane * 8] = pa;
      *(float4*)&pl[wave][lane * 8 + 4] = pb;
      int ng = deg - base; if (ng > 64) ng = 64;
      int t = 0;
      for (; t + 4 <= ng; t += 4) {
        uint2 s0 = swl[wave][t], s1 = swl[wave][t + 1];
        uint2 s2 = swl[wave][t + 2], s3 = swl[wave][t + 3];
        uint2 u0 = X2[(size_t)s0.x * 64];
        uint2 u1 = X2[(size_t)s1.x * 64];
        uint2 u2 = X2[(size_t)s2.x * 64];
        uint2 u3 = X2[(size_t)s3.x * 64];
        EDGE1(u0, s0, t)
        EDGE1(u1, s1, t + 1)
        EDGE1(u2, s2, t + 2)
        EDGE1(u3, s3, t + 3)
      }
      for (; t < ng; ++t) {
        uint2 s0 = swl[wave][t];
        uint2 u0 = X2[(size_t)s0.x * 64];
        EDGE1(u0, s0, t)
      }
    }
#undef EDGE1
    float4 i0 = *(const float4*)(linv + (size_t)d * 8);
    float4 i1 = *(const float4*)(linv + (size_t)d * 8 + 4);
    unsigned* ab = (unsigned*)aggbuf + (size_t)d * 512 + lane;
    ab[0]   = packbf(axp[0].x * i0.x, axp[0].y * i0.x);
    ab[64]  = packbf(axp[1].x * i0.y, axp[1].y * i0.y);
    ab[128] = packbf(axp[2].x * i0.z, axp[2].y * i0.z);
    ab[192] = packbf(axp[3].x * i0.w, axp[3].y * i0.w);
    ab[256] = packbf(axp[4].x * i1.x, axp[4].y * i1.x);
    ab[320] = packbf(axp[5].x * i1.y, axp[5].y * i1.y);
    ab[384] = packbf(axp[6].x * i1.z, axp[6].y * i1.z);
    ab[448] = packbf(axp[7].x * i1.w, axp[7].y * i1.w);
    float ginv = 1.f / fmaxf(wsum, 1e-16f);
    ((unsigned*)x2a)[(size_t)d * 64 + lane] = packbf(gp.x * ginv, gp.y * ginv);
  }
}

// =============================== host launch ===============================

extern "C" void kernel_launch(void* const* d_in, const int* in_sizes, int n_in,
                              void* d_out, int out_size, void* d_ws, size_t ws_size,
                              hipStream_t stream) {
  const float* x   = (const float*)d_in[0];
  const int*   ei  = (const int*)d_in[1];
  const float* ew  = (const float*)d_in[2];
  const float* W0  = (const float*)d_in[3];
  const float* a0s = (const float*)d_in[4];
  const float* a0d = (const float*)d_in[5];
  const float* W1  = (const float*)d_in[6];
  const float* a1s = (const float*)d_in[7];
  const float* a1d = (const float*)d_in[8];
  const float* gw0 = (const float*)d_in[9];
  const float* gw1 = (const float*)d_in[10];
  float* out = (float*)d_out;

  const int N = in_sizes[0] / 128;
  const int E = in_sizes[1] / 2;
  const int* src = ei;
  const int* dst = ei + E;

  // workspace carve (256B aligned); peak ~166 MB (= proven-safe envelope)
  char* p = (char*)d_ws;
  auto carve = [&](size_t bytes) {
    void* r = (void*)p;
    p += (bytes + 255) & ~(size_t)255;
    return r;
  };
  int*   cnt    = (int*)carve((size_t)N * 4);
  int*   rowptr = (int*)carve((size_t)(N + 1) * 4);
  int*   cur    = (int*)carve((size_t)N * 4);
  int*   bsum   = (int*)carve(256 * 4);
  uint2* edata  = (uint2*)carve((size_t)E * 8);
  unsigned short* W0catT  = (unsigned short*)carve(32768 * 2);
  float*          logitW  = (float*)carve(2048 * 4);
  unsigned short* gw1T    = (unsigned short*)carve(16384 * 2);
  unsigned short* va1T    = (unsigned short*)carve(2048 * 2);
  unsigned short* WstackT = (unsigned short*)carve(131072 * 2);
  float*          esed = (float*)carve((size_t)N * 16 * 4);
  unsigned short* xh   = (unsigned short*)carve((size_t)N * 512);   // [N][512B] interleaved
  unsigned short* x2a  = (unsigned short*)carve((size_t)N * 128 * 2);
  unsigned short* pedge = (unsigned short*)carve((size_t)E * 8 * 2); // layer0 then layer1
  float*          linv  = (float*)carve((size_t)N * 8 * 4);          // layer0 then layer1
  // scratch union: phase1 {xb | feat | logit0}; aggbuf [N,1024] bf16 overwrites
  // all of it after agg0 (nothing in scratch is read past agg0).
  size_t ph1 = ((size_t)N * 128 * 2 + 255) & ~(size_t)255;        // xb
  size_t ph2 = ph1 + (((size_t)N * 384 + 255) & ~(size_t)255);    // +feat [N][384B]
  size_t ph3 = ph2 + (((size_t)N * 16 * 4 + 255) & ~(size_t)255); // +logit0
  size_t scratch_sz = (size_t)N * 1024 * 2;  // aggbuf
  if (ph3 > scratch_sz) scratch_sz = ph3;
  char* scratch = (char*)carve(scratch_sz);
  unsigned short* xb     = (unsigned short*)scratch;
  unsigned short* feat   = (unsigned short*)(scratch + ph1);
  float*          logit0 = (float*)(scratch + ph2);
  unsigned short* aggbuf = (unsigned short*)scratch;  // alias, live after agg0

  int gE = (E + 255) / 256;
  int gE4 = ((E + 3) / 4 + 255) / 256;
  int nb = (N + 1023) / 1024;
  int gM = (N + 63) / 64;
  int gD = (N + 3) / 4;
  int gA = gD < 2048 ? gD : 2048;  // grid-stride agg kernels

  // Phase A1: counts + scan
  hipMemsetAsync(cnt, 0, (size_t)N * 4, stream);
  k_count<<<gE, 256, 0, stream>>>(dst, cnt, E);
  k_scan1<<<nb, 1024, 0, stream>>>(cnt, rowptr, bsum, N);
  k_scan2<<<1, 64, 0, stream>>>(bsum, rowptr + N, nb);
  k_scan3<<<nb, 1024, 0, stream>>>(rowptr, cur, bsum, N);

  // Phase A2: pure CSR scatter
  k_scatter<<<gE4, 256, 0, stream>>>(src, dst, ew, cur, edata, E);

  // weight packing + fused x-cast/logit0
  k_pack<<<(184320 + 255) / 256, 256, 0, stream>>>(W0, a0s, a0d, W1, a1s, a1d, gw0,
                                                   gw1, W0catT, logitW, gw1T, va1T,
                                                   WstackT);
  k_prep<<<(N + 15) / 16, 256, 0, stream>>>(x, logitW, xb, logit0, N);

  // layer-0 edge weights (isolated dispatch: logit0 stays L2-resident)
  k_pedge<<<gD, 256, 0, stream>>>(logit0, edata, rowptr, pedge, linv, N);

  // Phase B: feat [N][384B] = {bf16 Wh0 | fp8 gcn-h0} merged rows
  k_mgemm<8, 1, 4><<<dim3(gM, 2), 256, 0, stream>>>(xb, 128, W0catT, 128, feat, 192,
                                                    feat, N, 256, 128);
  // Phase C: layer-0 agg -> xh [N][512B] interleaved + esed [N,16] (fused GEMM-D)
  k_agg0<<<gA, 256, 0, stream>>>(feat, rowptr, edata, pedge, linv, va1T, xh, esed, N);

  // layer-1 edge weights (isolated dispatch; pedge/linv buffers reused)
  k_pedge<<<gD, 256, 0, stream>>>(esed, edata, rowptr, pedge, linv, N);

  // Phase E: layer-1 agg -> aggbuf [N,1024], x2a [N,128] (raw GCN agg, pre-proj)
  k_agg1<<<gA, 256, 0, stream>>>(xh, rowptr, edata, pedge, linv, aggbuf, x2a, N);

  // Phase F fused: out = max(aggbuf @ WstackT^T, relu(x2a @ gw1T^T))
  k_fin<<<gM, 256, 0, stream>>>(aggbuf, WstackT, x2a, gw1T, out, N);
}

// Round 7
// 449.062 us; speedup vs baseline: 1.0821x; 1.0821x over previous
//
#include <hip/hip_runtime.h>

#define LRELU_ALPHA 0.2f

typedef __attribute__((ext_vector_type(8))) short short8;
typedef __attribute__((ext_vector_type(4))) float float4v;
typedef __attribute__((ext_vector_type(2))) float f32x2;

__device__ __forceinline__ unsigned short f2bf(float f) {
  union { float f; unsigned u; } x; x.f = f;
  unsigned r = (x.u + 0x7fff + ((x.u >> 16) & 1)) >> 16;
  return (unsigned short)r;
}
__device__ __forceinline__ float bflo(unsigned u) {
  union { unsigned u; float f; } x; x.u = u << 16; return x.f;
}
__device__ __forceinline__ float bfhi(unsigned u) {
  union { unsigned u; float f; } x; x.u = u & 0xffff0000u; return x.f;
}
__device__ __forceinline__ f32x2 bfpair(unsigned u) {
  return (f32x2){bflo(u), bfhi(u)};
}
__device__ __forceinline__ unsigned packbf(float a, float b) {
  return (unsigned)f2bf(a) | ((unsigned)f2bf(b) << 16);
}

// =============================== Phase A: CSR build ===============================

__global__ __launch_bounds__(256) void k_count(const int* __restrict__ dst,
                                               int* __restrict__ cnt, int E) {
  int e = blockIdx.x * 256 + threadIdx.x;
  if (e < E) atomicAdd(&cnt[dst[e]], 1);
}

// wave-shfl scan (2 barriers instead of 20)
__global__ __launch_bounds__(1024) void k_scan1(const int* __restrict__ cnt,
                                                int* __restrict__ lscan,
                                                int* __restrict__ bsum, int N) {
  __shared__ int ws[16];
  int t = threadIdx.x, lane = t & 63, wid = t >> 6;
  int i = blockIdx.x * 1024 + t;
  int v = (i < N) ? cnt[i] : 0;
  int orig = v;
#pragma unroll
  for (int off = 1; off < 64; off <<= 1) {
    int y = __shfl_up(v, off, 64);
    if (lane >= off) v += y;
  }
  if (lane == 63) ws[wid] = v;
  __syncthreads();
  if (t < 16) {
    int s = ws[t], o = s;
#pragma unroll
    for (int off = 1; off < 16; off <<= 1) {
      int y = __shfl_up(s, off, 16);
      if (t >= off) s += y;
    }
    ws[t] = s - o;  // exclusive wave offsets
  }
  __syncthreads();
  if (i < N) lscan[i] = ws[wid] + v - orig;
  if (t == 1023) bsum[blockIdx.x] = ws[15] + v;
}

// one-wave shfl scan (nb <= 64)
__global__ __launch_bounds__(64) void k_scan2(int* __restrict__ bsum,
                                              int* __restrict__ rowptrN, int nb) {
  int t = threadIdx.x;
  int v = (t < nb) ? bsum[t] : 0;
  int orig = v;
  for (int off = 1; off < 64; off <<= 1) {
    int y = __shfl_up(v, off, 64);
    if (t >= off) v += y;
  }
  if (t < nb) bsum[t] = v - orig;
  if (t == 63) *rowptrN = v;
}

__global__ __launch_bounds__(1024) void k_scan3(int* __restrict__ rowptr,
                                                int* __restrict__ cur,
                                                const int* __restrict__ bsum, int N) {
  int i = blockIdx.x * 1024 + threadIdx.x;
  if (i < N) {
    int v = rowptr[i] + bsum[blockIdx.x];
    rowptr[i] = v;
    cur[i] = v;
  }
}

// scatter + fused layer-0 attention weights (round-0-proven): p computed from
// the small logit0 table (L2/L3-friendly; scatter has no big miss stream, so no
// thrash — the round-4 interference lesson applies to the agg kernels only).
__global__ __launch_bounds__(256) void k_scatter(const int* __restrict__ src,
                                                 const int* __restrict__ dst,
                                                 const float* __restrict__ w,
                                                 const float* __restrict__ logit0,
                                                 int* __restrict__ cur,
                                                 uint2* __restrict__ edata,
                                                 unsigned short* __restrict__ pedge,
                                                 int E) {
  int base = (blockIdx.x * 256 + threadIdx.x) * 4;
  if (base >= E) return;
  int n = E - base; if (n > 4) n = 4;
  int ss[4], dd[4]; float ww[4];
  if (n == 4) {
    int4 s4 = *(const int4*)(src + base);
    int4 d4 = *(const int4*)(dst + base);
    float4 w4 = *(const float4*)(w + base);
    ss[0] = s4.x; ss[1] = s4.y; ss[2] = s4.z; ss[3] = s4.w;
    dd[0] = d4.x; dd[1] = d4.y; dd[2] = d4.z; dd[3] = d4.w;
    ww[0] = w4.x; ww[1] = w4.y; ww[2] = w4.z; ww[3] = w4.w;
  } else {
    for (int i = 0; i < n; ++i) { ss[i] = src[base + i]; dd[i] = dst[base + i]; ww[i] = w[base + i]; }
  }
  int pp[4];
#pragma unroll
  for (int i = 0; i < 4; ++i)
    if (i < n) pp[i] = atomicAdd(&cur[dd[i]], 1);
#pragma unroll
  for (int i = 0; i < 4; ++i) {
    if (i >= n) break;
    int s = ss[i], d = dd[i], p = pp[i];
    edata[p] = make_uint2((unsigned)s, __float_as_uint(ww[i]));
    float4 es0 = *(const float4*)(logit0 + (size_t)s * 16);
    float4 es1 = *(const float4*)(logit0 + (size_t)s * 16 + 4);
    float4 ed0 = *(const float4*)(logit0 + (size_t)d * 16 + 8);
    float4 ed1 = *(const float4*)(logit0 + (size_t)d * 16 + 12);
    float lg[8] = {es0.x + ed0.x, es0.y + ed0.y, es0.z + ed0.z, es0.w + ed0.w,
                   es1.x + ed1.x, es1.y + ed1.y, es1.z + ed1.z, es1.w + ed1.w};
    unsigned short o[8];
#pragma unroll
    for (int h = 0; h < 8; ++h) {
      float v = lg[h] > 0.f ? lg[h] : LRELU_ALPHA * lg[h];
      o[h] = f2bf(__expf(fminf(v, 80.f)));
    }
    ushort4 q0 = {o[0], o[1], o[2], o[3]};
    ushort4 q1 = {o[4], o[5], o[6], o[7]};
    *(ushort4*)(pedge + (size_t)p * 8) = q0;
    *(ushort4*)(pedge + (size_t)p * 8 + 4) = q1;
  }
}

// =============================== weight packing ===============================
// W0catT bf16 [256][128]: rows 0..127 GAT n=h*16+f -> W0[h,k,f]; rows 128..255 gcn_W0[k][n-128]
// logitW  fp32 [128][16] : c<8: va0_src[k][h=c]; c>=8: va0_dst[k][h=c-8]
// gw1T    bf16 [128][128]: gw1T[n][k] = gcn_W1[k][n]
// va1T    bf16 [16][128] : c<8: W1[h=c]@a1_src; c>=8: W1[h]@a1_dst
// WstackT bf16 [128][1024]: WstackT[n][h*128+k] = W1[h][k][n] * 0.125
__global__ __launch_bounds__(256) void k_pack(const float* __restrict__ W0,
                                              const float* __restrict__ a0s,
                                              const float* __restrict__ a0d,
                                              const float* __restrict__ W1,
                                              const float* __restrict__ a1s,
                                              const float* __restrict__ a1d,
                                              const float* __restrict__ gw0,
                                              const float* __restrict__ gw1,
                                              unsigned short* __restrict__ W0catT,
                                              float* __restrict__ logitW,
                                              unsigned short* __restrict__ gw1T,
                                              unsigned short* __restrict__ va1T,
                                              unsigned short* __restrict__ WstackT) {
  int idx = blockIdx.x * 256 + threadIdx.x;
  if (idx < 32768) {
    int n = idx >> 7, k = idx & 127;
    float v;
    if (n < 128) {
      int h = n >> 4, f = n & 15;
      v = W0[h * 2048 + k * 16 + f];
    } else {
      v = gw0[k * 128 + (n - 128)];
    }
    W0catT[idx] = f2bf(v);
  } else if (idx < 34816) {
    int j = idx - 32768;
    int k = j >> 4, c = j & 15;
    int h = (c < 8) ? c : c - 8;
    const float* a = (c < 8) ? a0s : a0d;
    float s = 0.f;
    for (int f = 0; f < 16; ++f) s += W0[h * 2048 + k * 16 + f] * a[h * 16 + f];
    logitW[j] = s;
  } else if (idx < 51200) {
    int j = idx - 34816;
    int n = j >> 7, k = j & 127;
    gw1T[j] = f2bf(gw1[k * 128 + n]);
  } else if (idx < 53248) {
    int j = idx - 51200;
    int c = j >> 7, k = j & 127;
    int h = c & 7;
    const float* a = (c < 8) ? a1s : a1d;
    float s = 0.f;
    for (int f = 0; f < 128; ++f) s += W1[h * 16384 + k * 128 + f] * a[h * 128 + f];
    va1T[j] = f2bf(s);
  } else if (idx < 184320) {
    int j = idx - 53248;
    int n = j >> 10, kk = j & 1023;
    int h = kk >> 7, k = kk & 127;
    WstackT[j] = f2bf(W1[h * 16384 + k * 128 + n] * 0.125f);
  }
}

// fused: xb = bf16(x), logit0[N,16] = x @ logitW; 16 rows per block
__global__ __launch_bounds__(256) void k_prep(const float* __restrict__ x,
                                              const float* __restrict__ logitW,
                                              unsigned short* __restrict__ xb,
                                              float* __restrict__ logit0, int N) {
  __shared__ float sm[16][132];
  __shared__ float sw[2048];
  int t = threadIdx.x;
  int base = blockIdx.x * 16;
  int r = t >> 4, cc = (t & 15) * 8;
  const float* xr = x + (size_t)(base + r) * 128 + cc;
  float4 v0 = *(const float4*)xr;
  float4 v1 = *(const float4*)(xr + 4);
  ushort4 o0 = {f2bf(v0.x), f2bf(v0.y), f2bf(v0.z), f2bf(v0.w)};
  ushort4 o1 = {f2bf(v1.x), f2bf(v1.y), f2bf(v1.z), f2bf(v1.w)};
  *(ushort4*)(xb + (size_t)(base + r) * 128 + cc) = o0;
  *(ushort4*)(xb + (size_t)(base + r) * 128 + cc + 4) = o1;
  *(float4*)&sm[r][cc] = v0;
  *(float4*)&sm[r][cc + 4] = v1;
  *(float4*)&sw[t * 8] = *(const float4*)(logitW + t * 8);
  *(float4*)&sw[t * 8 + 4] = *(const float4*)(logitW + t * 8 + 4);
  __syncthreads();
  int c = t & 15;
  float acc = 0.f;
#pragma unroll
  for (int k = 0; k < 128; ++k) acc += sm[r][k] * sw[k * 16 + c];
  logit0[(size_t)(base + r) * 16 + c] = acc;
}

// =============================== edge-weight precompute (layer 1) ===============================
// ISOLATED dispatch so the [N,16] esed table stays L2-resident (round-4 lesson).
__global__ __launch_bounds__(256) void k_pedge(const float* __restrict__ logits,
                                               const uint2* __restrict__ edata,
                                               const int* __restrict__ rowptr,
                                               unsigned short* __restrict__ pedge,
                                               float* __restrict__ linv, int N) {
  int wave = threadIdx.x >> 6, lane = threadIdx.x & 63;
  int d = blockIdx.x * 4 + wave;
  if (d >= N) return;
  int j8 = lane >> 3, h = lane & 7;
  float edv = logits[(size_t)d * 16 + 8 + h];
  int beg = rowptr[d], end = rowptr[d + 1];
  float lsum = 0.f;
  for (int ii = beg + j8; ii < end; ii += 8) {
    unsigned s = edata[ii].x;
    float es = logits[(size_t)s * 16 + h];
    float lg = es + edv;
    lg = lg > 0.f ? lg : LRELU_ALPHA * lg;
    float p = __expf(fminf(lg, 80.f));
    lsum += p;
    pedge[(size_t)ii * 8 + h] = f2bf(p);
  }
  lsum += __shfl_xor(lsum, 8, 64);
  lsum += __shfl_xor(lsum, 16, 64);
  lsum += __shfl_xor(lsum, 32, 64);
  if (lane < 8) linv[(size_t)d * 8 + h] = lsum > 0.f ? 1.f / lsum : 0.f;
}

// =============================== bf16 MFMA GEMM ===============================
// C = A[M,K] @ BT[Ncols,K]^T.
// EPI: 0 plain, 1 max(acc, bf16 aux), 5 relu + bf16 write (in-place GCN proj),
//      4 merged feat write: cc<128 -> bf16 at rr*192+cc; cc>=128 -> fp8 byte at
//         rr*384 + 256 + (cc-128)  (one [N][384B] row: 256B bf16 + 128B fp8)
template <int NT, int OUT_BF16, int EPI>
__global__ __launch_bounds__(256) void k_mgemm(const unsigned short* __restrict__ A, int lda,
                                               const unsigned short* __restrict__ BT, int ldb,
                                               void* __restrict__ Cv, int ldc,
                                               const void* __restrict__ aux,
                                               int M, int Ncols, int K) {
  __shared__ unsigned short As[64][64];
  __shared__ unsigned short Bs[NT * 16][64];
  int tid = threadIdx.x;
  int w = tid >> 6, lane = tid & 63;
  int quad = lane >> 4, l16 = lane & 15;
  int row0 = blockIdx.x * 64;
  int c0 = blockIdx.y * (NT * 16);
  float4v acc[NT];
#pragma unroll
  for (int t = 0; t < NT; ++t) acc[t] = (float4v){0.f, 0.f, 0.f, 0.f};

  for (int k0 = 0; k0 < K; k0 += 64) {
    __syncthreads();
#pragma unroll
    for (int i = 0; i < 2; ++i) {
      int c = tid + i * 256;
      int r = c >> 3, kc = c & 7;
      uint4 v = {0u, 0u, 0u, 0u};
      int gr = row0 + r;
      if (gr < M) v = *(const uint4*)(A + (size_t)gr * lda + k0 + kc * 8);
      *(uint4*)(&As[r][(kc ^ (r & 7)) * 8]) = v;
    }
#pragma unroll
    for (int i = 0; i < (NT * 128 + 255) / 256; ++i) {
      int c = tid + i * 256;
      if (c < NT * 128) {
        int n = c >> 3, kc = c & 7;
        uint4 v = {0u, 0u, 0u, 0u};
        int gn = c0 + n;
        if (gn < Ncols) v = *(const uint4*)(BT + (size_t)gn * ldb + k0 + kc * 8);
        *(uint4*)(&Bs[n][(kc ^ (n & 7)) * 8]) = v;
      }
    }
    __syncthreads();
#pragma unroll
    for (int ks = 0; ks < 2; ++ks) {
      int m = w * 16 + l16;
      int ga = (ks * 4 + quad) ^ (m & 7);
      short8 a = *(const short8*)(&As[m][ga * 8]);
#pragma unroll
      for (int t = 0; t < NT; ++t) {
        int n = t * 16 + l16;
        int gb = (ks * 4 + quad) ^ (n & 7);
        short8 b = *(const short8*)(&Bs[n][gb * 8]);
        acc[t] = __builtin_amdgcn_mfma_f32_16x16x32_bf16(a, b, acc[t], 0, 0, 0);
      }
    }
  }
#pragma unroll
  for (int t = 0; t < NT; ++t) {
    int cc = c0 + t * 16 + l16;
    if (cc >= Ncols) continue;
#pragma unroll
    for (int i = 0; i < 4; ++i) {
      int rr = row0 + w * 16 + quad * 4 + i;
      if (rr >= M) continue;
      float v = acc[t][i];
      if (EPI == 1) {
        unsigned short us = ((const unsigned short*)aux)[(size_t)rr * ldc + cc];
        v = fmaxf(v, bflo((unsigned)us));
      }
      if (EPI == 5) v = fmaxf(v, 0.f);
      if (EPI == 4) {
        if (cc < 128) {
          ((unsigned short*)Cv)[(size_t)rr * 192 + cc] = f2bf(v);
        } else {
          int enc = __builtin_amdgcn_cvt_pk_fp8_f32(v, v, 0, false);
          ((unsigned char*)aux)[(size_t)rr * 384 + 256 + (cc - 128)] = (unsigned char)(enc & 0xff);
        }
      } else if (OUT_BF16)
        ((unsigned short*)Cv)[(size_t)rr * ldc + cc] = f2bf(v);
      else
        ((float*)Cv)[(size_t)rr * ldc + cc] = v;
    }
  }
}

// =============================== Phase C: layer-0 aggregation ==============
// feat [N][384B] merged: [0,256) bf16 Wh0 pairs, [256,384) fp8 gcn-h0 pairs.
// p's staged from pedge (written by fused scatter). Softmax denominator summed
// INTERNALLY: full-wave layout means every lane walks every edge, so each
// lane's l (for its head) is complete — no reduce, no linv input.
// Outputs: xh [N][512B] = 64 x uint2 { bf16 x1c pair | bf16 relu'd x2 pair }
// + compact x1cc [N,128] bf16 for the Phase-D GEMM.
__global__ __launch_bounds__(256, 8) void k_agg0(const unsigned short* __restrict__ feat,
                                                 const int* __restrict__ rowptr,
                                                 const uint2* __restrict__ edata,
                                                 const unsigned short* __restrict__ pedge,
                                                 unsigned short* __restrict__ xh,
                                                 unsigned short* __restrict__ x1cc, int N) {
  __shared__ uint2 swl[4][64];
  __shared__ float pl[4][512];
  int wave = threadIdx.x >> 6, lane = threadIdx.x & 63;
  int head = lane >> 3;
  const char* FG = (const char*)feat + lane * 4;        // + s*384: bf16 pair
  const char* FC = (const char*)feat + 256 + lane * 2;  // + s*384: fp8 pair
  for (int d = blockIdx.x * 4 + wave; d < N; d += gridDim.x * 4) {
    int beg = rowptr[d], end = rowptr[d + 1], deg = end - beg;
    f32x2 aa = {0.f, 0.f}, ga = {0.f, 0.f};
    float l = 0.f, wsum = 0.f;
    for (int base = 0; base < deg; base += 64) {
      int idx = beg + base + lane;
      uint2 sv = make_uint2(0u, 0u);
      uint4 q = make_uint4(0u, 0u, 0u, 0u);
      if (idx < end) {
        sv = edata[idx];
        q = *(const uint4*)(pedge + (size_t)idx * 8);
      }
      swl[wave][lane] = sv;
      float4 pa = make_float4(bflo(q.x), bfhi(q.x), bflo(q.y), bfhi(q.y));
      float4 pb = make_float4(bflo(q.z), bfhi(q.z), bflo(q.w), bfhi(q.w));
      *(float4*)&pl[wave][lane * 8] = pa;
      *(float4*)&pl[wave][lane * 8 + 4] = pb;
      int ng = deg - base; if (ng > 64) ng = 64;
      int t = 0;
      for (; t + 4 <= ng; t += 4) {
        uint2 s0 = swl[wave][t], s1 = swl[wave][t + 1];
        uint2 s2 = swl[wave][t + 2], s3 = swl[wave][t + 3];
        unsigned g0 = *(const unsigned*)(FG + (size_t)s0.x * 384);
        unsigned g1 = *(const unsigned*)(FG + (size_t)s1.x * 384);
        unsigned g2 = *(const unsigned*)(FG + (size_t)s2.x * 384);
        unsigned g3 = *(const unsigned*)(FG + (size_t)s3.x * 384);
        unsigned c0 = *(const unsigned short*)(FC + (size_t)s0.x * 384);
        unsigned c1 = *(const unsigned short*)(FC + (size_t)s1.x * 384);
        unsigned c2 = *(const unsigned short*)(FC + (size_t)s2.x * 384);
        unsigned c3 = *(const unsigned short*)(FC + (size_t)s3.x * 384);
        float p0 = pl[wave][t * 8 + head];
        float p1 = pl[wave][t * 8 + 8 + head];
        float p2 = pl[wave][t * 8 + 16 + head];
        float p3 = pl[wave][t * 8 + 24 + head];
        float w0 = __uint_as_float(s0.y), w1 = __uint_as_float(s1.y);
        float w2 = __uint_as_float(s2.y), w3 = __uint_as_float(s3.y);
        aa += bfpair(g0) * p0; ga += __builtin_amdgcn_cvt_pk_f32_fp8(c0, false) * w0;
        l += p0; wsum += w0;
        aa += bfpair(g1) * p1; ga += __builtin_amdgcn_cvt_pk_f32_fp8(c1, false) * w1;
        l += p1; wsum += w1;
        aa += bfpair(g2) * p2; ga += __builtin_amdgcn_cvt_pk_f32_fp8(c2, false) * w2;
        l += p2; wsum += w2;
        aa += bfpair(g3) * p3; ga += __builtin_amdgcn_cvt_pk_f32_fp8(c3, false) * w3;
        l += p3; wsum += w3;
      }
      for (; t < ng; ++t) {
        uint2 s0 = swl[wave][t];
        unsigned g0 = *(const unsigned*)(FG + (size_t)s0.x * 384);
        unsigned c0 = *(const unsigned short*)(FC + (size_t)s0.x * 384);
        float p0 = pl[wave][t * 8 + head];
        float w0 = __uint_as_float(s0.y);
        aa += bfpair(g0) * p0; ga += __builtin_amdgcn_cvt_pk_f32_fp8(c0, false) * w0;
        l += p0; wsum += w0;
      }
    }
    float inv = l > 0.f ? 1.f / l : 0.f;
    float v0 = aa.x * inv, v1 = aa.y * inv;
    v0 = v0 > 0.f ? v0 : __expf(v0) - 1.f;  // ELU
    v1 = v1 > 0.f ? v1 : __expf(v1) - 1.f;
    float ginv = 1.f / fmaxf(wsum, 1e-16f);
    unsigned px = packbf(v0, v1);
    ((uint2*)xh)[(size_t)d * 64 + lane] =
        make_uint2(px, packbf(fmaxf(ga.x * ginv, 0.f), fmaxf(ga.y * ginv, 0.f)));
    ((unsigned*)x1cc)[(size_t)d * 64 + lane] = px;
  }
}

// =============================== Phase E: layer-1 aggregation ==============
// ONE uint2 (8B)/lane gather covers the full interleaved 512B xh row per edge:
// .x = bf16 x1c pair (GAT), .y = bf16 raw-x2 pair (GCN, projection deferred).
// p's staged from precomputed pedge; linv precomputed (isolated k_pedge).
// Writes aggbuf [N,1024] bf16 + x2a [N,128] bf16 (raw; projected after).
__global__ __launch_bounds__(256, 8) void k_agg1(const unsigned short* __restrict__ xh,
                                                 const int* __restrict__ rowptr,
                                                 const uint2* __restrict__ edata,
                                                 const unsigned short* __restrict__ pedge,
                                                 const float* __restrict__ linv,
                                                 unsigned short* __restrict__ aggbuf,
                                                 unsigned short* __restrict__ x2a, int N) {
  __shared__ uint2 swl[4][64];
  __shared__ float pl[4][512];
  int wave = threadIdx.x >> 6, lane = threadIdx.x & 63;
  const uint2* X2 = (const uint2*)xh + lane;
  for (int d = blockIdx.x * 4 + wave; d < N; d += gridDim.x * 4) {
    int beg = rowptr[d], end = rowptr[d + 1], deg = end - beg;
    f32x2 axp[8] = {};
    f32x2 gp = {0.f, 0.f};
    float wsum = 0.f;
#define EDGE1(uu, ss, tt)                                    \
  {                                                          \
    float4 pv0 = *(const float4*)&pl[wave][(tt) * 8];        \
    float4 pv1 = *(const float4*)&pl[wave][(tt) * 8 + 4];    \
    float wj = __uint_as_float((ss).y);                      \
    f32x2 xA = bfpair((uu).x);                               \
    f32x2 hA = bfpair((uu).y);                               \
    axp[0] += xA * pv0.x; axp[1] += xA * pv0.y;              \
    axp[2] += xA * pv0.z; axp[3] += xA * pv0.w;              \
    axp[4] += xA * pv1.x; axp[5] += xA * pv1.y;              \
    axp[6] += xA * pv1.z; axp[7] += xA * pv1.w;              \
    gp += hA * wj; wsum += wj;                               \
  }
    for (int base = 0; base < deg; base += 64) {
      int idx = beg + base + lane;
      uint2 sv = make_uint2(0u, 0u);
      uint4 q = make_uint4(0u, 0u, 0u, 0u);
      if (idx < end) {
        sv = edata[idx];
        q = *(const uint4*)(pedge + (size_t)idx * 8);
      }
      swl[wave][lane] = sv;
      float4 pa = make_float4(bflo(q.x), bfhi(q.x), bflo(q.y), bfhi(q.y));
      float4 pb = make_float4(bflo(q.z), bfhi(q.z), bflo(q.w), bfhi(q.w));
      *(float4*)&pl[wave][lane * 8] = pa;
      *(float4*)&pl[wave][lane * 8 + 4] = pb;
      int ng = deg - base; if (ng > 64) ng = 64;
      int t = 0;
      for (; t + 4 <= ng; t += 4) {
        uint2 s0 = swl[wave][t], s1 = swl[wave][t + 1];
        uint2 s2 = swl[wave][t + 2], s3 = swl[wave][t + 3];
        uint2 u0 = X2[(size_t)s0.x * 64];
        uint2 u1 = X2[(size_t)s1.x * 64];
        uint2 u2 = X2[(size_t)s2.x * 64];
        uint2 u3 = X2[(size_t)s3.x * 64];
        EDGE1(u0, s0, t)
        EDGE1(u1, s1, t + 1)
        EDGE1(u2, s2, t + 2)
        EDGE1(u3, s3, t + 3)
      }
      for (; t < ng; ++t) {
        uint2 s0 = swl[wave][t];
        uint2 u0 = X2[(size_t)s0.x * 64];
        EDGE1(u0, s0, t)
      }
    }
#undef EDGE1
    float4 i0 = *(const float4*)(linv + (size_t)d * 8);
    float4 i1 = *(const float4*)(linv + (size_t)d * 8 + 4);
    unsigned* ab = (unsigned*)aggbuf + (size_t)d * 512 + lane;
    ab[0]   = packbf(axp[0].x * i0.x, axp[0].y * i0.x);
    ab[64]  = packbf(axp[1].x * i0.y, axp[1].y * i0.y);
    ab[128] = packbf(axp[2].x * i0.z, axp[2].y * i0.z);
    ab[192] = packbf(axp[3].x * i0.w, axp[3].y * i0.w);
    ab[256] = packbf(axp[4].x * i1.x, axp[4].y * i1.x);
    ab[320] = packbf(axp[5].x * i1.y, axp[5].y * i1.y);
    ab[384] = packbf(axp[6].x * i1.z, axp[6].y * i1.z);
    ab[448] = packbf(axp[7].x * i1.w, axp[7].y * i1.w);
    float ginv = 1.f / fmaxf(wsum, 1e-16f);
    ((unsigned*)x2a)[(size_t)d * 64 + lane] = packbf(gp.x * ginv, gp.y * ginv);
  }
}

// =============================== host launch ===============================

extern "C" void kernel_launch(void* const* d_in, const int* in_sizes, int n_in,
                              void* d_out, int out_size, void* d_ws, size_t ws_size,
                              hipStream_t stream) {
  const float* x   = (const float*)d_in[0];
  const int*   ei  = (const int*)d_in[1];
  const float* ew  = (const float*)d_in[2];
  const float* W0  = (const float*)d_in[3];
  const float* a0s = (const float*)d_in[4];
  const float* a0d = (const float*)d_in[5];
  const float* W1  = (const float*)d_in[6];
  const float* a1s = (const float*)d_in[7];
  const float* a1d = (const float*)d_in[8];
  const float* gw0 = (const float*)d_in[9];
  const float* gw1 = (const float*)d_in[10];
  float* out = (float*)d_out;

  const int N = in_sizes[0] / 128;
  const int E = in_sizes[1] / 2;
  const int* src = ei;
  const int* dst = ei + E;

  // workspace carve (256B aligned); peak ~166 MB (= proven-safe envelope)
  char* p = (char*)d_ws;
  auto carve = [&](size_t bytes) {
    void* r = (void*)p;
    p += (bytes + 255) & ~(size_t)255;
    return r;
  };
  int*   cnt    = (int*)carve((size_t)N * 4);
  int*   rowptr = (int*)carve((size_t)(N + 1) * 4);
  int*   cur    = (int*)carve((size_t)N * 4);
  int*   bsum   = (int*)carve(256 * 4);
  uint2* edata  = (uint2*)carve((size_t)E * 8);
  unsigned short* W0catT  = (unsigned short*)carve(32768 * 2);
  float*          logitW  = (float*)carve(2048 * 4);
  unsigned short* gw1T    = (unsigned short*)carve(16384 * 2);
  unsigned short* va1T    = (unsigned short*)carve(2048 * 2);
  unsigned short* WstackT = (unsigned short*)carve(131072 * 2);
  float*          esed = (float*)carve((size_t)N * 16 * 4);
  unsigned short* xh   = (unsigned short*)carve((size_t)N * 512);   // [N][512B] interleaved
  unsigned short* x2a  = (unsigned short*)carve((size_t)N * 128 * 2);
  unsigned short* pedge = (unsigned short*)carve((size_t)E * 8 * 2); // layer0 then layer1
  float*          linv  = (float*)carve((size_t)N * 8 * 4);          // layer1
  // scratch union: phase1 {xb | feat | logit0}; x1cc aliases xb (dead after GEMM-B);
  // aggbuf [N,1024] bf16 overwrites all after GEMM-D reads x1cc.
  size_t ph1 = ((size_t)N * 128 * 2 + 255) & ~(size_t)255;        // xb / x1cc
  size_t ph2 = ph1 + (((size_t)N * 384 + 255) & ~(size_t)255);    // +feat [N][384B]
  size_t ph3 = ph2 + (((size_t)N * 16 * 4 + 255) & ~(size_t)255); // +logit0
  size_t scratch_sz = (size_t)N * 1024 * 2;  // aggbuf
  if (ph3 > scratch_sz) scratch_sz = ph3;
  char* scratch = (char*)carve(scratch_sz);
  unsigned short* xb     = (unsigned short*)scratch;
  unsigned short* x1cc   = (unsigned short*)scratch;  // alias of xb (dead after GEMM-B)
  unsigned short* feat   = (unsigned short*)(scratch + ph1);
  float*          logit0 = (float*)(scratch + ph2);
  unsigned short* aggbuf = (unsigned short*)scratch;  // alias, live after GEMM-D

  int gE = (E + 255) / 256;
  int gE4 = ((E + 3) / 4 + 255) / 256;
  int nb = (N + 1023) / 1024;
  int gM = (N + 63) / 64;
  int gD = (N + 3) / 4;
  int gA = gD < 2048 ? gD : 2048;  // grid-stride agg kernels

  // Phase A1: counts + scan
  hipMemsetAsync(cnt, 0, (size_t)N * 4, stream);
  k_count<<<gE, 256, 0, stream>>>(dst, cnt, E);
  k_scan1<<<nb, 1024, 0, stream>>>(cnt, rowptr, bsum, N);
  k_scan2<<<1, 64, 0, stream>>>(bsum, rowptr + N, nb);
  k_scan3<<<nb, 1024, 0, stream>>>(rowptr, cur, bsum, N);

  // weight packing + fused x-cast/logit0 (before scatter: scatter consumes logit0)
  k_pack<<<(184320 + 255) / 256, 256, 0, stream>>>(W0, a0s, a0d, W1, a1s, a1d, gw0,
                                                   gw1, W0catT, logitW, gw1T, va1T,
                                                   WstackT);
  k_prep<<<(N + 15) / 16, 256, 0, stream>>>(x, logitW, xb, logit0, N);

  // Phase A2: scatter + fused layer-0 attention weights (round-0-proven)
  k_scatter<<<gE4, 256, 0, stream>>>(src, dst, ew, logit0, cur, edata, pedge, E);

  // Phase B: feat [N][384B] = {bf16 Wh0 | fp8 gcn-h0} merged rows
  k_mgemm<8, 1, 4><<<dim3(gM, 2), 256, 0, stream>>>(xb, 128, W0catT, 128, feat, 192,
                                                    feat, N, 256, 128);
  // Phase C: layer-0 agg (internal softmax denom) -> xh interleaved + x1cc
  k_agg0<<<gA, 256, 0, stream>>>(feat, rowptr, edata, pedge, xh, x1cc, N);

  // Phase D: esed[N,16] fp32 = x1cc @ va1T^T
  k_mgemm<1, 0, 0><<<dim3(gM, 1), 256, 0, stream>>>(x1cc, 128, va1T, 128, esed, 16,
                                                    nullptr, N, 16, 128);

  // layer-1 edge weights (isolated dispatch; pedge buffer reused)
  k_pedge<<<gD, 256, 0, stream>>>(esed, edata, rowptr, pedge, linv, N);

  // Phase E: layer-1 agg -> aggbuf [N,1024], x2a [N,128] (raw GCN agg, pre-proj)
  k_agg1<<<gA, 256, 0, stream>>>(xh, rowptr, edata, pedge, linv, aggbuf, x2a, N);

  // GCN projection post-aggregation (linearity): x2a = relu(x2a @ gw1T), in-place
  k_mgemm<8, 1, 5><<<dim3(gM, 1), 256, 0, stream>>>(x2a, 128, gw1T, 128, x2a, 128,
                                                    nullptr, N, 128, 128);

  // Phase F: out = max(aggbuf @ WstackT^T, x2a)
  k_mgemm<8, 0, 1><<<dim3(gM, 1), 256, 0, stream>>>(aggbuf, 1024, WstackT, 1024, out,
                                                    128, x2a, N, 128, 1024);
}